// Round 3
// 92.584 us; speedup vs baseline: 1.0822x; 1.0822x over previous
//
#include <hip/hip_runtime.h>
#include <math.h>

// NetVLAD: B=8, N=2048, D=128, K=64, fp32 in/out.
#define BB 8
#define NN 2048
#define DD 128
#define KK 64
#define PP 128           // blocks per batch for K1 (1024 blocks = 4/CU)
#define NPB (NN / PP)    // 16 descriptors per block, processed in ONE pass

// ---------------------------------------------------------------------------
// K1 v3: single-pass, 2 barriers, plain HIP (no global_load_lds).
//   load:     each thread loads 8 floats of "its" descriptor row (i0 = t>>4)
//             straight into registers (coalesced dwordx4 pairs); centroid
//             fragments + ||c||^2 reduce overlap the load latency.
//   norm:     4-shfl reduce over the 16-lane row group, scale in registers,
//             write the NORMALIZED row to LDS once.
//   bar 1
//   Phase B:  16 unrolled dot+exp chains; per-wave softmax partial via
//             3 intra-wave shfl (the wave's 16 k's) -> sL[i][wave].
//   bar 2
//   Phase C:  16 unrolled accumulate chains; denominators via one float4
//             broadcast read of sL.
// vs round-0 kernel: 8 barrier-fenced phases -> 2; no per-iteration
// global-load dependency chain; no 64-wide rsum phase. Identical math and
// partial layout.
// ---------------------------------------------------------------------------
__global__ __launch_bounds__(256, 4) void netvlad_k1(
    const float* __restrict__ x, const float* __restrict__ cent,
    float* __restrict__ part_acc, float* __restrict__ part_sA)
{
    const int b    = blockIdx.x >> 7;    // / PP
    const int p    = blockIdx.x & 127;   // % PP
    const int t    = threadIdx.x;
    const int kq   = t >> 3;             // 0..31: owns k = {2kq, 2kq+1}
    const int pr   = t & 7;              // 0..7: owns d-range [pr*16, +16)
    const int dbase = pr * 16;
    const int wave = t >> 6;

    __shared__ __align__(16) float xs[NPB][DD];  // 8 KB: normalized descriptors
    __shared__ __align__(16) float sL[NPB][4];   // per-wave exp-sum partials

    // Rotated chunk offsets: register slot jj -> physical d-chunk
    // ((jj+pr)&3) inside this thread's 16-float range (2-way bank alias max).
    int off[4];
    #pragma unroll
    for (int jj = 0; jj < 4; ++jj) off[jj] = dbase + (((jj + pr) & 3) << 2);

    // ---- issue x loads first: thread t owns row i0 = t>>4, floats
    // [tl*4, +4) and [64+tl*4, +4). Fully coalesced 16B/lane.
    const int i0 = t >> 4, tl = t & 15;
    const float* xr = x + ((size_t)b * NN + (size_t)p * NPB + i0) * DD;
    float4 v0 = *(const float4*)(xr + tl * 4);
    float4 v1 = *(const float4*)(xr + 64 + tl * 4);

    // ---- centroid fragments + ||c_k||^2 (independent chain, overlaps x loads)
    float4 cA[4], cB[4];
    float cn2a = 0.f, cn2b = 0.f;
    #pragma unroll
    for (int jj = 0; jj < 4; ++jj) {
        cA[jj] = *(const float4*)(cent + (2 * kq) * DD + off[jj]);
        cB[jj] = *(const float4*)(cent + (2 * kq + 1) * DD + off[jj]);
        cn2a += cA[jj].x*cA[jj].x + cA[jj].y*cA[jj].y + cA[jj].z*cA[jj].z + cA[jj].w*cA[jj].w;
        cn2b += cB[jj].x*cB[jj].x + cB[jj].y*cB[jj].y + cB[jj].z*cB[jj].z + cB[jj].w*cB[jj].w;
    }
    #pragma unroll
    for (int m = 1; m < 8; m <<= 1) {
        cn2a += __shfl_xor(cn2a, m);
        cn2b += __shfl_xor(cn2b, m);
    }

    // ---- normalize row i0 in registers (16 lanes per row, 4-shfl reduce),
    // write the normalized row to LDS once.
    {
        float ss = v0.x*v0.x + v0.y*v0.y + v0.z*v0.z + v0.w*v0.w
                 + v1.x*v1.x + v1.y*v1.y + v1.z*v1.z + v1.w*v1.w;
        #pragma unroll
        for (int m = 1; m < 16; m <<= 1) ss += __shfl_xor(ss, m);
        const float rn = 1.0f / fmaxf(sqrtf(ss), 1e-12f);
        v0.x *= rn; v0.y *= rn; v0.z *= rn; v0.w *= rn;
        v1.x *= rn; v1.y *= rn; v1.z *= rn; v1.w *= rn;
        *(float4*)(&xs[i0][tl * 4])      = v0;
        *(float4*)(&xs[i0][64 + tl * 4]) = v1;
    }
    __syncthreads();   // bar 1: normalized tile visible to all

    // ---- Phase B: dots + exp, 16 independent chains. assign ∝ exp(||c||^2 - 2 xn·c)
    float e0[NPB], e1[NPB];
    #pragma unroll
    for (int i = 0; i < NPB; ++i) {
        float S0 = 0.f, S1 = 0.f;
        #pragma unroll
        for (int jj = 0; jj < 4; ++jj) {
            float4 v = *(const float4*)(&xs[i][off[jj]]);
            S0 += v.x*cA[jj].x + v.y*cA[jj].y + v.z*cA[jj].z + v.w*cA[jj].w;
            S1 += v.x*cB[jj].x + v.y*cB[jj].y + v.z*cB[jj].z + v.w*cB[jj].w;
        }
        #pragma unroll
        for (int m = 1; m < 8; m <<= 1) {   // reduce across the 8 d-parts
            S0 += __shfl_xor(S0, m);
            S1 += __shfl_xor(S1, m);
        }
        e0[i] = __expf(cn2a - 2.f * S0);
        e1[i] = __expf(cn2b - 2.f * S1);
        // per-wave softmax partial: sum this wave's 16 k's (kq bits = 3,4,5)
        float es = e0[i] + e1[i];
        #pragma unroll
        for (int m = 8; m < 64; m <<= 1) es += __shfl_xor(es, m);
        if ((t & 63) == 0) sL[i][wave] = es;
    }
    __syncthreads();   // bar 2: sL complete

    // ---- Phase C: accumulate assign * xn into register tile
    float4 acc0[4], acc1[4];
    #pragma unroll
    for (int jj = 0; jj < 4; ++jj) {
        acc0[jj] = make_float4(0.f, 0.f, 0.f, 0.f);
        acc1[jj] = make_float4(0.f, 0.f, 0.f, 0.f);
    }
    float sA0 = 0.f, sA1 = 0.f;
    #pragma unroll
    for (int i = 0; i < NPB; ++i) {
        const float4 s4 = *(const float4*)(&sL[i][0]);   // 16B-aligned broadcast
        const float rs = 1.0f / (s4.x + s4.y + s4.z + s4.w);
        const float a0 = e0[i] * rs, a1 = e1[i] * rs;
        sA0 += a0; sA1 += a1;
        #pragma unroll
        for (int jj = 0; jj < 4; ++jj) {
            float4 v = *(const float4*)(&xs[i][off[jj]]);
            acc0[jj].x += a0*v.x; acc0[jj].y += a0*v.y; acc0[jj].z += a0*v.z; acc0[jj].w += a0*v.w;
            acc1[jj].x += a1*v.x; acc1[jj].y += a1*v.y; acc1[jj].z += a1*v.z; acc1[jj].w += a1*v.w;
        }
    }

    // ---- epilogue: write partial accumulators
    const size_t base = (size_t)(b * PP + p) * KK * DD;
    #pragma unroll
    for (int jj = 0; jj < 4; ++jj) {
        *(float4*)(part_acc + base + (2 * kq) * DD + off[jj])     = acc0[jj];
        *(float4*)(part_acc + base + (2 * kq + 1) * DD + off[jj]) = acc1[jj];
    }
    if (pr == 0) {
        part_sA[(b * PP + p) * KK + 2 * kq]     = sA0;
        part_sA[(b * PP + p) * KK + 2 * kq + 1] = sA1;
    }
}

// ---------------------------------------------------------------------------
// K2: reduce 128 partials per (b,k), subtract c*sumA, intra-normalize, and
// apply the global L2 factor (sqrt(K)=8 folded as 0.125; error ~1e-8 vs
// 5.5e-4 threshold). Grid: BB*KK = 512 blocks of 128 threads.
// ---------------------------------------------------------------------------
__global__ __launch_bounds__(128) void netvlad_k2(
    const float* __restrict__ cent, const float* __restrict__ part_acc,
    const float* __restrict__ part_sA, float* __restrict__ out)
{
    const int b  = blockIdx.x >> 6;
    const int k  = blockIdx.x & 63;
    const int t  = threadIdx.x;
    const int d4 = t & 31;
    const int ps = t >> 5;

    // ---- sumA: 128 threads, one partial each, block-reduce
    __shared__ float sAL[2];
    {
        float sA = part_sA[(b * PP + t) * KK + k];
        #pragma unroll
        for (int m = 1; m < 64; m <<= 1) sA += __shfl_xor(sA, m);
        if ((t & 63) == 0) sAL[t >> 6] = sA;
    }

    // ---- vlad partial sum: each thread sums 32 p's for its float4 column
    float4 acc = make_float4(0.f, 0.f, 0.f, 0.f);
    const float* base = part_acc + ((size_t)(b * PP) * KK + k) * DD + d4 * 4;
    #pragma unroll 8
    for (int pp = 0; pp < 32; ++pp) {
        const float4 v = *(const float4*)(base + (size_t)(ps * 32 + pp) * KK * DD);
        acc.x += v.x; acc.y += v.y; acc.z += v.z; acc.w += v.w;
    }

    __shared__ float4 red[4][32];
    red[ps][d4] = acc;
    __syncthreads();
    const float sAt = sAL[0] + sAL[1];

    if (t < 32) {
        float4 v = red[0][t];
        #pragma unroll
        for (int s = 1; s < 4; ++s) {
            v.x += red[s][t].x; v.y += red[s][t].y;
            v.z += red[s][t].z; v.w += red[s][t].w;
        }
        const float4 c = *(const float4*)(cent + k * DD + t * 4);
        v.x -= c.x * sAt; v.y -= c.y * sAt; v.z -= c.z * sAt; v.w -= c.w * sAt;

        float ss = v.x*v.x + v.y*v.y + v.z*v.z + v.w*v.w;
        #pragma unroll
        for (int m = 1; m < 32; m <<= 1) ss += __shfl_xor(ss, m);
        const float rn = 0.125f / fmaxf(sqrtf(ss), 1e-12f);
        v.x *= rn; v.y *= rn; v.z *= rn; v.w *= rn;
        *(float4*)(out + ((size_t)b * KK + k) * DD + t * 4) = v;
    }
}

extern "C" void kernel_launch(void* const* d_in, const int* in_sizes, int n_in,
                              void* d_out, int out_size, void* d_ws, size_t ws_size,
                              hipStream_t stream) {
    const float* x    = (const float*)d_in[0];   // [8, 2048, 128] fp32
    const float* cent = (const float*)d_in[1];   // [64, 128] fp32
    float* out = (float*)d_out;                  // [8, 8192] fp32

    char* ws = (char*)d_ws;
    float* part_sA  = (float*)ws;                 // 8*128*64 fp32 = 256 KB
    float* part_acc = (float*)(ws + (1 << 19));   // 8*128*64*128 fp32 = 32 MB

    netvlad_k1<<<dim3(BB * PP), dim3(256), 0, stream>>>(x, cent, part_acc, part_sA);
    netvlad_k2<<<dim3(BB * KK), dim3(128), 0, stream>>>(cent, part_acc, part_sA, out);
}